// Round 9
// baseline (358.874 us; speedup 1.0000x reference)
//
#include <hip/hip_runtime.h>

#define BB 64
#define TT 4096
#define KK 48
#define UST 56              // stage1 Ubuf col stride (bf16): 112 B
#define PST 56              // phase LDS col stride (bf16)
#define WS_LS_OFF 16384
#define WS_U_OFF 32768
#define SEGBYTES 6144       // 48 rows x 64 col-stride x bf16

typedef __bf16 bf16_t;
typedef bf16_t bf16x8 __attribute__((ext_vector_type(8)));
typedef float f32x4 __attribute__((ext_vector_type(4)));
typedef float f32x16 __attribute__((ext_vector_type(16)));

__device__ __forceinline__ float fexp(float x) {   // natural exp
    return __builtin_amdgcn_exp2f(x * 1.4426950408889634f);
}
__device__ __forceinline__ float flog2(float x) { return __builtin_amdgcn_logf(x); }
__device__ __forceinline__ float rdlanef(float v, int l) {
    return __int_as_float(__builtin_amdgcn_readlane(__float_as_int(v), l));
}
__device__ __forceinline__ unsigned int bf16bits(float f) {
    return (unsigned int)__builtin_bit_cast(unsigned short, (bf16_t)f);
}
__device__ __forceinline__ float bf2f(bf16_t h) {
    return __uint_as_float(((unsigned int)__builtin_bit_cast(unsigned short, h)) << 16);
}
// pack two fp32 -> bf16x2 by truncation (1 v_perm_b32); lo in low half
__device__ __forceinline__ unsigned int pktrunc(float lo, float hi) {
    return __builtin_amdgcn_perm(__float_as_uint(hi), __float_as_uint(lo), 0x07060302u);
}

// ============ fused: stage1 (waves 0-2) + ex-staging & scores (wave 3) ============
__global__ __launch_bounds__(256, 8) void fused_kernel(
    const float* __restrict__ y_true, const float* __restrict__ y_pred,
    const float* __restrict__ trans, float* __restrict__ ws_target,
    int* __restrict__ ws_ls, bf16_t* __restrict__ ws_u, int nseg) {
    const int s = blockIdx.x, b = blockIdx.y;
    const int seglen = TT / nseg;
    const int nch = seglen / 64;
    const int tid = threadIdx.x;
    const int w = tid >> 6;
    const int lane = tid & 63;
    const int q = lane >> 4;
    const int n = lane & 15;
    const int ncol = 16 * w + n;

    __shared__ __align__(16) float4 exf[64 * 13];             // fp32 ex, stride 13
    __shared__ __align__(16) bf16_t Ubuf[48 * UST + 16];
    __shared__ unsigned long long pb;
    __shared__ int lsb[4];

    // A fragments (waves 0-2): E^T zero-padded in K. A[m][k]: m=16mt+n, k=32ks+8q+j.
    bf16x8 afrag[3][2];
    if (w < 3) {
#pragma unroll
        for (int mt = 0; mt < 3; mt++) {
#pragma unroll
            for (int ks = 0; ks < 2; ks++) {
                bf16x8 f;
#pragma unroll
                for (int j = 0; j < 8; j++) {
                    int k = 32 * ks + 8 * q + j;
                    float v = (k < KK) ? fexp(trans[k * KK + 16 * mt + n]) : 0.0f;
                    f[j] = (bf16_t)v;
                }
                afrag[mt][ks] = f;
            }
        }
    }

    {   // zero Ubuf then identity diag
        uint4* p = (uint4*)Ubuf;
        for (int i = tid; i < (48 * UST + 16) / 8; i += 256) p[i] = make_uint4(0, 0, 0, 0);
    }
    __syncthreads();
    if (tid < KK) Ubuf[tid * UST + tid] = (bf16_t)1.0f;

    const bf16_t* bptr0 = &Ubuf[ncol * UST + 8 * q];
    const bf16_t* bptr1 = &Ubuf[ncol * UST + 32 + 8 * q];
    bf16_t* wp0 = &Ubuf[ncol * UST + 0 + 4 * q];
    bf16_t* wp1 = &Ubuf[ncol * UST + 16 + 4 * q];
    bf16_t* wp2 = &Ubuf[ncol * UST + 32 + 4 * q];

    f32x4 z4 = {0.0f, 0.0f, 0.0f, 0.0f};
    int ls = 0;
    int cnt = 0;          // unmasked steps since last rescale (wave-uniform)
    float sc_acc = 0.0f;  // wave3: scores accumulator

    for (int ch = 0; ch < nch; ch++) {
        __syncthreads();                     // previous exf fully consumed
        if (w == 3) {
            // ---- producer + scores: lane = local timestep ----
            const int t0c = s * seglen + ch * 64;
            const size_t rowbase = ((size_t)b * TT + t0c + lane) * KK;
            const float4* yp4 = (const float4*)(y_pred + rowbase);
            const float4* yt4 = (const float4*)(y_true + rowbase);
            float dot = 0.0f, labf = 0.0f, pmin = 1e30f;
            float4* exrow = &exf[lane * 13];
#pragma unroll 4
            for (int g = 0; g < 12; g++) {
                float4 p = yp4[g];
                float4 a = yt4[g];
                dot = fmaf(a.x, p.x, fmaf(a.y, p.y, fmaf(a.z, p.z, fmaf(a.w, p.w, dot))));
                float e0 = (float)(4 * g);
                labf = fmaf(a.x, e0, fmaf(a.y, e0 + 1.0f, fmaf(a.z, e0 + 2.0f, fmaf(a.w, e0 + 3.0f, labf))));
                pmin = fminf(pmin, fminf(fminf(p.x, p.y), fminf(p.z, p.w)));
                exrow[g] = make_float4(fexp(p.x), fexp(p.y), fexp(p.z), fexp(p.w));
            }
            bool mt_ok = pmin > -1e6f;
            unsigned long long bal = __ballot(mt_ok);
            if (lane == 0) pb = bal;

            // boundary row t0c+64 (label+mask), lanes 0..11 partials
            float labB = 0.0f, pmB = 1e30f;
            const bool hasB = (t0c + 64 < TT);
            if (hasB && lane < 12) {
                const size_t bdbase = ((size_t)b * TT + t0c + 64) * KK;
                float4 a = ((const float4*)(y_true + bdbase))[lane];
                float4 p = ((const float4*)(y_pred + bdbase))[lane];
                float e0 = (float)(4 * lane);
                labB = fmaf(a.x, e0, fmaf(a.y, e0 + 1.0f, fmaf(a.z, e0 + 2.0f, a.w * (e0 + 3.0f))));
                pmB = fminf(fminf(p.x, p.y), fminf(p.z, p.w));
            }
#pragma unroll
            for (int off = 1; off < 16; off <<= 1) {
                labB += __shfl_xor(labB, off);
                pmB = fminf(pmB, __shfl_xor(pmB, off));
            }
            int labB_i = (int)(rdlanef(labB, 0) + 0.5f);
            float mB = (hasB && rdlanef(pmB, 0) > -1e6f) ? 1.0f : 0.0f;

            int labt = (int)(labf + 0.5f);
            float mft = mt_ok ? 1.0f : 0.0f;
            int lnx = __shfl(labt, (lane + 1) & 63);
            float mnx = __shfl(mft, (lane + 1) & 63);
            if (lane == 63) { lnx = labB_i; mnx = mB; }
            sc_acc += mft * dot + mft * mnx * trans[labt * KK + lnx];
        }
        __syncthreads();
        if (w < 3) {
            const unsigned long long mk = pb;
            const int tt0 = (s == 0 && ch == 0) ? 1 : 0;
            for (int tt = tt0; tt < 64; tt++) {
                if (!((mk >> tt) & 1ull)) continue;

                bf16x8 bf0 = __builtin_bit_cast(bf16x8, *(const uint4*)bptr0);
                bf16x8 bf1 = __builtin_bit_cast(bf16x8, *(const uint4*)bptr1);

                f32x4 acc0 = __builtin_amdgcn_mfma_f32_16x16x32_bf16(afrag[0][0], bf0, z4, 0, 0, 0);
                acc0 = __builtin_amdgcn_mfma_f32_16x16x32_bf16(afrag[0][1], bf1, acc0, 0, 0, 0);
                f32x4 acc1 = __builtin_amdgcn_mfma_f32_16x16x32_bf16(afrag[1][0], bf0, z4, 0, 0, 0);
                acc1 = __builtin_amdgcn_mfma_f32_16x16x32_bf16(afrag[1][1], bf1, acc1, 0, 0, 0);
                f32x4 acc2 = __builtin_amdgcn_mfma_f32_16x16x32_bf16(afrag[2][0], bf0, z4, 0, 0, 0);
                acc2 = __builtin_amdgcn_mfma_f32_16x16x32_bf16(afrag[2][1], bf1, acc2, 0, 0, 0);

                float4 ex0 = exf[tt * 13 + q];        // ex rows 4q..4q+3
                float4 ex1 = exf[tt * 13 + 4 + q];    // ex rows 16+4q..
                float4 ex2 = exf[tt * 13 + 8 + q];    // ex rows 32+4q..

                // deferred pow2 rescale: every 6 unmasked steps (overflow-safe;
                // bf16/fp32 share 8-bit exponent; k extraction is exact)
                if (++cnt >= 6) {
                    float v00 = rdlanef(acc0[0], 0);
                    int k = (int)(__float_as_uint(v00) >> 23) - 127;
                    float r = __uint_as_float((unsigned int)(127 - k) << 23);
                    ls += k;
                    ex0.x *= r; ex0.y *= r; ex0.z *= r; ex0.w *= r;
                    ex1.x *= r; ex1.y *= r; ex1.z *= r; ex1.w *= r;
                    ex2.x *= r; ex2.y *= r; ex2.z *= r; ex2.w *= r;
                    cnt = 0;
                }

                *(uint2*)wp0 = make_uint2(pktrunc(acc0[0] * ex0.x, acc0[1] * ex0.y),
                                          pktrunc(acc0[2] * ex0.z, acc0[3] * ex0.w));
                *(uint2*)wp1 = make_uint2(pktrunc(acc1[0] * ex1.x, acc1[1] * ex1.y),
                                          pktrunc(acc1[2] * ex1.z, acc1[3] * ex1.w));
                *(uint2*)wp2 = make_uint2(pktrunc(acc2[0] * ex2.x, acc2[1] * ex2.y),
                                          pktrunc(acc2[2] * ex2.z, acc2[3] * ex2.w));
            }
        }
    }

    // wave3: per-block scores partial (no atomic; every slot written)
    if (w == 3) {
#pragma unroll
        for (int off = 32; off; off >>= 1) sc_acc += __shfl_xor(sc_acc, off);
        if (lane == 0) ws_target[b * nseg + s] = sc_acc;
    }

    // reconcile per-wave pow2 scales (exact), write compact 48x64 bf16 block
    if (w < 3 && lane == 0) lsb[w] = ls;
    __syncthreads();
    if (w < 3 && lane < KK) {
        const int dl = ls - lsb[0];
        bf16_t* Uo = ws_u + (size_t)(b * nseg + s) * 3072;
        unsigned int wd[8];
#pragma unroll
        for (int j = 0; j < 8; j++) {
            float f0 = ldexpf(bf2f(Ubuf[(16 * w + 2 * j) * UST + lane]), dl);
            float f1 = ldexpf(bf2f(Ubuf[(16 * w + 2 * j + 1) * UST + lane]), dl);
            wd[j] = bf16bits(f0) | (bf16bits(f1) << 16);
        }
        *(uint4*)(Uo + (size_t)lane * 64 + 16 * w) = make_uint4(wd[0], wd[1], wd[2], wd[3]);
        *(uint4*)(Uo + (size_t)lane * 64 + 16 * w + 8) = make_uint4(wd[4], wd[5], wd[6], wd[7]);
    }
    if (tid == 0) ws_ls[b * nseg + s] = lsb[0];
}

// 48x48 product: D = A (global row-major 48x64) x W (LDS col-major stride PST), in place.
// Returns pow2 scale exponent removed. No barriers inside (single-wave safe).
__device__ __forceinline__ int chain_product(const bf16_t* __restrict__ A, bf16_t* Ub, int lane) {
    const int half = lane >> 5;
    const int l31 = lane & 31;
    f32x16 z16;
#pragma unroll
    for (int r = 0; r < 16; r++) z16[r] = 0.0f;

    bf16x8 af[2][3];
#pragma unroll
    for (int mt = 0; mt < 2; mt++) {
        int m = l31 + 32 * mt;
#pragma unroll
        for (int ks = 0; ks < 3; ks++) {
            if (m < KK)
                af[mt][ks] = __builtin_bit_cast(bf16x8, *(const uint4*)&A[(size_t)m * 64 + 16 * ks + 8 * half]);
            else
                af[mt][ks] = __builtin_bit_cast(bf16x8, make_uint4(0, 0, 0, 0));
        }
    }
    bf16x8 bg[3][2];
#pragma unroll
    for (int ks = 0; ks < 3; ks++)
#pragma unroll
        for (int nt = 0; nt < 2; nt++)
            bg[ks][nt] = __builtin_bit_cast(bf16x8, *(const uint4*)&Ub[(l31 + 32 * nt) * PST + 16 * ks + 8 * half]);

    f32x16 acc[4];
#pragma unroll
    for (int mt = 0; mt < 2; mt++)
#pragma unroll
        for (int nt = 0; nt < 2; nt++) {
            f32x16 a0 = __builtin_amdgcn_mfma_f32_32x32x16_bf16(af[mt][0], bg[0][nt], z16, 0, 0, 0);
            a0 = __builtin_amdgcn_mfma_f32_32x32x16_bf16(af[mt][1], bg[1][nt], a0, 0, 0, 0);
            acc[mt * 2 + nt] = __builtin_amdgcn_mfma_f32_32x32x16_bf16(af[mt][2], bg[2][nt], a0, 0, 0, 0);
        }

    float v00 = rdlanef(acc[0][0], 0);
    int k = (int)(__float_as_uint(v00) >> 23) - 127;
    float r = __uint_as_float((unsigned int)(127 - k) << 23);

#pragma unroll
    for (int mt = 0; mt < 2; mt++)
#pragma unroll
        for (int nt = 0; nt < 2; nt++) {
            int c = l31 + 32 * nt;
#pragma unroll
            for (int g = 0; g < 4; g++) {
                int a0 = 32 * mt + 8 * g + 4 * half;
                if (a0 < KK) {
                    const f32x16& Aq = acc[mt * 2 + nt];
                    unsigned int u0 = bf16bits(Aq[4 * g + 0] * r) | (bf16bits(Aq[4 * g + 1] * r) << 16);
                    unsigned int u1 = bf16bits(Aq[4 * g + 2] * r) | (bf16bits(Aq[4 * g + 3] * r) << 16);
                    *(uint2*)&Ub[c * PST + a0] = make_uint2(u0, u1);
                }
            }
        }
    return k;
}

// Variant: A read from LDS col-major slot (A[m][k] = As[k*PST + m]).
__device__ __forceinline__ int chain_product_ldsA(const bf16_t* As, bf16_t* Ub, int lane) {
    const int half = lane >> 5;
    const int l31 = lane & 31;
    f32x16 z16;
#pragma unroll
    for (int r = 0; r < 16; r++) z16[r] = 0.0f;

    bf16x8 af[2][3];
#pragma unroll
    for (int mt = 0; mt < 2; mt++) {
        int m = l31 + 32 * mt;
#pragma unroll
        for (int ks = 0; ks < 3; ks++) {
            bf16x8 f;
#pragma unroll
            for (int j = 0; j < 8; j++) {
                int k = 16 * ks + 8 * half + j;
                f[j] = (m < KK) ? As[k * PST + m] : (bf16_t)0.0f;
            }
            af[mt][ks] = f;
        }
    }
    bf16x8 bg[3][2];
#pragma unroll
    for (int ks = 0; ks < 3; ks++)
#pragma unroll
        for (int nt = 0; nt < 2; nt++)
            bg[ks][nt] = __builtin_bit_cast(bf16x8, *(const uint4*)&Ub[(l31 + 32 * nt) * PST + 16 * ks + 8 * half]);

    f32x16 acc[4];
#pragma unroll
    for (int mt = 0; mt < 2; mt++)
#pragma unroll
        for (int nt = 0; nt < 2; nt++) {
            f32x16 a0 = __builtin_amdgcn_mfma_f32_32x32x16_bf16(af[mt][0], bg[0][nt], z16, 0, 0, 0);
            a0 = __builtin_amdgcn_mfma_f32_32x32x16_bf16(af[mt][1], bg[1][nt], a0, 0, 0, 0);
            acc[mt * 2 + nt] = __builtin_amdgcn_mfma_f32_32x32x16_bf16(af[mt][2], bg[2][nt], a0, 0, 0, 0);
        }

    float v00 = rdlanef(acc[0][0], 0);
    int k = (int)(__float_as_uint(v00) >> 23) - 127;
    float r = __uint_as_float((unsigned int)(127 - k) << 23);

#pragma unroll
    for (int mt = 0; mt < 2; mt++)
#pragma unroll
        for (int nt = 0; nt < 2; nt++) {
            int c = l31 + 32 * nt;
#pragma unroll
            for (int g = 0; g < 4; g++) {
                int a0 = 32 * mt + 8 * g + 4 * half;
                if (a0 < KK) {
                    const f32x16& Aq = acc[mt * 2 + nt];
                    unsigned int u0 = bf16bits(Aq[4 * g + 0] * r) | (bf16bits(Aq[4 * g + 1] * r) << 16);
                    unsigned int u1 = bf16bits(Aq[4 * g + 2] * r) | (bf16bits(Aq[4 * g + 3] * r) << 16);
                    *(uint2*)&Ub[c * PST + a0] = make_uint2(u0, u1);
                }
            }
        }
    return k;
}

// ============ phaseAB: one kernel — 4-wave fold of all segments + q0 + output ============
__global__ __launch_bounds__(256) void phaseAB_kernel(
    const float* __restrict__ y_pred, const bf16_t* __restrict__ ws_u,
    const int* __restrict__ ws_ls, const float* __restrict__ ws_target,
    float* __restrict__ out, int nseg) {
    const int b = blockIdx.x;
    const int tid = threadIdx.x;
    const int w = tid >> 6;
    const int lane = tid & 63;
    const int per = nseg / 4;       // segments per wave

    __shared__ __align__(16) bf16_t Ws[4][64 * PST];   // 4 x 7 KB
    __shared__ int lsw[4];

    // wave w: load its first segment, fold the remaining per-1 serially
    const int base = b * nseg + w * per;
    const bf16_t* s0 = ws_u + (size_t)base * 3072;
    for (int k = 0; k < KK; k++)
        Ws[w][lane * PST + k] = (lane < KK) ? s0[(size_t)k * 64 + lane] : (bf16_t)0.0f;
    int lsk = ws_ls[base];
    for (int j = 1; j < per; j++) {
        const bf16_t* A = ws_u + (size_t)(base + j) * 3072;
        lsk += ws_ls[base + j];
        lsk += chain_product(A, Ws[w], lane);
    }
    if (lane == 0) lsw[w] = lsk;
    __syncthreads();

    if (w == 0) {
        int ls2 = 0;
#pragma unroll
        for (int j = 1; j < 4; j++) ls2 += chain_product_ldsA(Ws[j], Ws[0], lane);

        float L = (float)(lsw[0] + lsw[1] + lsw[2] + lsw[3] + ls2);

        // q0 from t=0 row
        float x0 = (lane < KK) ? y_pred[(size_t)b * TT * KK + lane] : 0.0f;
        bool ok0 = (lane >= KK) || (x0 > -1e6f);
        bool m0 = (__ballot(ok0) == ~0ull);
        float xeff = (lane < KK) ? (m0 ? x0 : 0.0f) : 0.0f;
        float c0 = rdlanef(xeff, 0);
        float q0 = (lane < KK) ? fexp(xeff - c0) : 0.0f;

        float p = 0.0f;
        if (lane < KK) {
            for (int c = 0; c < KK; c++) {
                float qc = rdlanef(q0, c);
                p = fmaf(bf2f(Ws[0][c * PST + lane]), qc, p);
            }
        }
#pragma unroll
        for (int off = 32; off; off >>= 1) p += __shfl_xor(p, off);

        // target = sum of per-block partials
        float tg = (lane < nseg) ? ws_target[b * nseg + lane] : 0.0f;
#pragma unroll
        for (int off = 32; off; off >>= 1) tg += __shfl_xor(tg, off);

        if (lane == 0) {
            out[b] = c0 + 0.6931471805599453f * (L + flog2(p)) - tg;
        }
    }
}

extern "C" void kernel_launch(void* const* d_in, const int* in_sizes, int n_in,
                              void* d_out, int out_size, void* d_ws, size_t ws_size,
                              hipStream_t stream) {
    const float* y_true = (const float*)d_in[0];
    const float* y_pred = (const float*)d_in[1];
    const float* trans = (const float*)d_in[2];
    float* out = (float*)d_out;

    // adaptive segment count (r3 lesson: never overrun d_ws)
    int nseg = 16;
    if (ws_size >= (size_t)WS_U_OFF + (size_t)BB * 64 * SEGBYTES) nseg = 64;
    else if (ws_size >= (size_t)WS_U_OFF + (size_t)BB * 32 * SEGBYTES) nseg = 32;

    float* ws_target = (float*)d_ws;                          // BB*nseg floats (<=16 KB)
    int* ws_ls = (int*)((char*)d_ws + WS_LS_OFF);             // BB*nseg ints  (<=16 KB)
    bf16_t* ws_u = (bf16_t*)((char*)d_ws + WS_U_OFF);

    fused_kernel<<<dim3(nseg, BB), 256, 0, stream>>>(
        y_true, y_pred, trans, ws_target, ws_ls, ws_u, nseg);
    phaseAB_kernel<<<BB, 256, 0, stream>>>(y_pred, ws_u, ws_ls, ws_target, out, nseg);
}

// Round 10
// 270.158 us; speedup vs baseline: 1.3284x; 1.3284x over previous
//
#include <hip/hip_runtime.h>

#define BB 64
#define TT 4096
#define KK 48
#define UST 56              // stage1 Ubuf col stride (bf16): 112 B
#define PST 56              // phase LDS col stride (bf16)
#define WS_LS_OFF 16384
#define WS_U_OFF 32768
#define SEGBYTES 6144       // 48 rows x 64 col-stride x bf16

typedef __bf16 bf16_t;
typedef bf16_t bf16x8 __attribute__((ext_vector_type(8)));
typedef float f32x4 __attribute__((ext_vector_type(4)));
typedef float f32x16 __attribute__((ext_vector_type(16)));

__device__ __forceinline__ float fexp(float x) {   // natural exp
    return __builtin_amdgcn_exp2f(x * 1.4426950408889634f);
}
__device__ __forceinline__ float flog2(float x) { return __builtin_amdgcn_logf(x); }
__device__ __forceinline__ float rdlanef(float v, int l) {
    return __int_as_float(__builtin_amdgcn_readlane(__float_as_int(v), l));
}
__device__ __forceinline__ unsigned int bf16bits(float f) {
    return (unsigned int)__builtin_bit_cast(unsigned short, (bf16_t)f);
}
__device__ __forceinline__ float bf2f(bf16_t h) {
    return __uint_as_float(((unsigned int)__builtin_bit_cast(unsigned short, h)) << 16);
}
// pack two fp32 -> bf16x2 by truncation (1 v_perm_b32); lo in low half
__device__ __forceinline__ unsigned int pktrunc(float lo, float hi) {
    return __builtin_amdgcn_perm(__float_as_uint(hi), __float_as_uint(lo), 0x07060302u);
}

// ============ fused: stage1 (waves 0-2) + ex-staging & scores (wave 3) ============
// NOTE: no min-waves in launch_bounds — (256,6)/(256,8) forced VGPR 40/32 and the
// kernel spilled to scratch (r9: WRITE_SIZE 154 MB, VALUBusy 23%). Plain (256)
// gives VGPR ~64 -> no spill; LDS 18.9 KB still allows 8 blocks/CU.
__global__ __launch_bounds__(256) void fused_kernel(
    const float* __restrict__ y_true, const float* __restrict__ y_pred,
    const float* __restrict__ trans, float* __restrict__ ws_target,
    int* __restrict__ ws_ls, bf16_t* __restrict__ ws_u, int nseg) {
    const int s = blockIdx.x, b = blockIdx.y;
    const int seglen = TT / nseg;
    const int nch = seglen / 64;
    const int tid = threadIdx.x;
    const int w = tid >> 6;
    const int lane = tid & 63;
    const int q = lane >> 4;
    const int n = lane & 15;
    const int ncol = 16 * w + n;

    __shared__ __align__(16) float4 exf[64 * 13];             // fp32 ex, stride 13
    __shared__ __align__(16) bf16_t Ubuf[48 * UST + 16];
    __shared__ unsigned long long pb;
    __shared__ int lsb[4];

    // A fragments (waves 0-2): E^T zero-padded in K. A[m][k]: m=16mt+n, k=32ks+8q+j.
    bf16x8 afrag[3][2];
    if (w < 3) {
#pragma unroll
        for (int mt = 0; mt < 3; mt++) {
#pragma unroll
            for (int ks = 0; ks < 2; ks++) {
                bf16x8 f;
#pragma unroll
                for (int j = 0; j < 8; j++) {
                    int k = 32 * ks + 8 * q + j;
                    float v = (k < KK) ? fexp(trans[k * KK + 16 * mt + n]) : 0.0f;
                    f[j] = (bf16_t)v;
                }
                afrag[mt][ks] = f;
            }
        }
    }

    {   // zero Ubuf then identity diag
        uint4* p = (uint4*)Ubuf;
        for (int i = tid; i < (48 * UST + 16) / 8; i += 256) p[i] = make_uint4(0, 0, 0, 0);
    }
    __syncthreads();
    if (tid < KK) Ubuf[tid * UST + tid] = (bf16_t)1.0f;

    const bf16_t* bptr0 = &Ubuf[ncol * UST + 8 * q];
    const bf16_t* bptr1 = &Ubuf[ncol * UST + 32 + 8 * q];
    bf16_t* wp0 = &Ubuf[ncol * UST + 0 + 4 * q];
    bf16_t* wp1 = &Ubuf[ncol * UST + 16 + 4 * q];
    bf16_t* wp2 = &Ubuf[ncol * UST + 32 + 4 * q];

    f32x4 z4 = {0.0f, 0.0f, 0.0f, 0.0f};
    int ls = 0;
    int cnt = 0;          // unmasked steps since last rescale (wave-uniform)
    float sc_acc = 0.0f;  // wave3: scores accumulator

    for (int ch = 0; ch < nch; ch++) {
        __syncthreads();                     // previous exf fully consumed
        if (w == 3) {
            // ---- producer + scores: lane = local timestep ----
            const int t0c = s * seglen + ch * 64;
            const size_t rowbase = ((size_t)b * TT + t0c + lane) * KK;
            const float4* yp4 = (const float4*)(y_pred + rowbase);
            const float4* yt4 = (const float4*)(y_true + rowbase);
            float dot = 0.0f, labf = 0.0f, pmin = 1e30f;
            float4* exrow = &exf[lane * 13];
#pragma unroll 4
            for (int g = 0; g < 12; g++) {
                float4 p = yp4[g];
                float4 a = yt4[g];
                dot = fmaf(a.x, p.x, fmaf(a.y, p.y, fmaf(a.z, p.z, fmaf(a.w, p.w, dot))));
                float e0 = (float)(4 * g);
                labf = fmaf(a.x, e0, fmaf(a.y, e0 + 1.0f, fmaf(a.z, e0 + 2.0f, fmaf(a.w, e0 + 3.0f, labf))));
                pmin = fminf(pmin, fminf(fminf(p.x, p.y), fminf(p.z, p.w)));
                exrow[g] = make_float4(fexp(p.x), fexp(p.y), fexp(p.z), fexp(p.w));
            }
            bool mt_ok = pmin > -1e6f;
            unsigned long long bal = __ballot(mt_ok);
            if (lane == 0) pb = bal;

            // boundary row t0c+64 (label+mask), lanes 0..11 partials
            float labB = 0.0f, pmB = 1e30f;
            const bool hasB = (t0c + 64 < TT);
            if (hasB && lane < 12) {
                const size_t bdbase = ((size_t)b * TT + t0c + 64) * KK;
                float4 a = ((const float4*)(y_true + bdbase))[lane];
                float4 p = ((const float4*)(y_pred + bdbase))[lane];
                float e0 = (float)(4 * lane);
                labB = fmaf(a.x, e0, fmaf(a.y, e0 + 1.0f, fmaf(a.z, e0 + 2.0f, a.w * (e0 + 3.0f))));
                pmB = fminf(fminf(p.x, p.y), fminf(p.z, p.w));
            }
#pragma unroll
            for (int off = 1; off < 16; off <<= 1) {
                labB += __shfl_xor(labB, off);
                pmB = fminf(pmB, __shfl_xor(pmB, off));
            }
            int labB_i = (int)(rdlanef(labB, 0) + 0.5f);
            float mB = (hasB && rdlanef(pmB, 0) > -1e6f) ? 1.0f : 0.0f;

            int labt = (int)(labf + 0.5f);
            float mft = mt_ok ? 1.0f : 0.0f;
            int lnx = __shfl(labt, (lane + 1) & 63);
            float mnx = __shfl(mft, (lane + 1) & 63);
            if (lane == 63) { lnx = labB_i; mnx = mB; }
            sc_acc += mft * dot + mft * mnx * trans[labt * KK + lnx];
        }
        __syncthreads();
        if (w < 3) {
            const unsigned long long mk = pb;
            const int tt0 = (s == 0 && ch == 0) ? 1 : 0;
            for (int tt = tt0; tt < 64; tt++) {
                if (!((mk >> tt) & 1ull)) continue;

                bf16x8 bf0 = __builtin_bit_cast(bf16x8, *(const uint4*)bptr0);
                bf16x8 bf1 = __builtin_bit_cast(bf16x8, *(const uint4*)bptr1);

                f32x4 acc0 = __builtin_amdgcn_mfma_f32_16x16x32_bf16(afrag[0][0], bf0, z4, 0, 0, 0);
                acc0 = __builtin_amdgcn_mfma_f32_16x16x32_bf16(afrag[0][1], bf1, acc0, 0, 0, 0);
                f32x4 acc1 = __builtin_amdgcn_mfma_f32_16x16x32_bf16(afrag[1][0], bf0, z4, 0, 0, 0);
                acc1 = __builtin_amdgcn_mfma_f32_16x16x32_bf16(afrag[1][1], bf1, acc1, 0, 0, 0);
                f32x4 acc2 = __builtin_amdgcn_mfma_f32_16x16x32_bf16(afrag[2][0], bf0, z4, 0, 0, 0);
                acc2 = __builtin_amdgcn_mfma_f32_16x16x32_bf16(afrag[2][1], bf1, acc2, 0, 0, 0);

                float4 ex0 = exf[tt * 13 + q];        // ex rows 4q..4q+3
                float4 ex1 = exf[tt * 13 + 4 + q];    // ex rows 16+4q..
                float4 ex2 = exf[tt * 13 + 8 + q];    // ex rows 32+4q..

                // deferred pow2 rescale: every 6 unmasked steps (overflow-safe;
                // per-step growth < 2^13, 6 steps < 2^78 << fp32/bf16 max 2^127)
                if (++cnt >= 6) {
                    float v00 = rdlanef(acc0[0], 0);
                    int k = (int)(__float_as_uint(v00) >> 23) - 127;
                    float r = __uint_as_float((unsigned int)(127 - k) << 23);
                    ls += k;
                    ex0.x *= r; ex0.y *= r; ex0.z *= r; ex0.w *= r;
                    ex1.x *= r; ex1.y *= r; ex1.z *= r; ex1.w *= r;
                    ex2.x *= r; ex2.y *= r; ex2.z *= r; ex2.w *= r;
                    cnt = 0;
                }

                *(uint2*)wp0 = make_uint2(pktrunc(acc0[0] * ex0.x, acc0[1] * ex0.y),
                                          pktrunc(acc0[2] * ex0.z, acc0[3] * ex0.w));
                *(uint2*)wp1 = make_uint2(pktrunc(acc1[0] * ex1.x, acc1[1] * ex1.y),
                                          pktrunc(acc1[2] * ex1.z, acc1[3] * ex1.w));
                *(uint2*)wp2 = make_uint2(pktrunc(acc2[0] * ex2.x, acc2[1] * ex2.y),
                                          pktrunc(acc2[2] * ex2.z, acc2[3] * ex2.w));
            }
        }
    }

    // wave3: per-block scores partial (no atomic; every slot written)
    if (w == 3) {
#pragma unroll
        for (int off = 32; off; off >>= 1) sc_acc += __shfl_xor(sc_acc, off);
        if (lane == 0) ws_target[b * nseg + s] = sc_acc;
    }

    // reconcile per-wave pow2 scales (exact), write compact 48x64 bf16 block
    if (w < 3 && lane == 0) lsb[w] = ls;
    __syncthreads();
    if (w < 3 && lane < KK) {
        const int dl = ls - lsb[0];
        bf16_t* Uo = ws_u + (size_t)(b * nseg + s) * 3072;
        unsigned int wd[8];
#pragma unroll
        for (int j = 0; j < 8; j++) {
            float f0 = ldexpf(bf2f(Ubuf[(16 * w + 2 * j) * UST + lane]), dl);
            float f1 = ldexpf(bf2f(Ubuf[(16 * w + 2 * j + 1) * UST + lane]), dl);
            wd[j] = bf16bits(f0) | (bf16bits(f1) << 16);
        }
        *(uint4*)(Uo + (size_t)lane * 64 + 16 * w) = make_uint4(wd[0], wd[1], wd[2], wd[3]);
        *(uint4*)(Uo + (size_t)lane * 64 + 16 * w + 8) = make_uint4(wd[4], wd[5], wd[6], wd[7]);
    }
    if (tid == 0) ws_ls[b * nseg + s] = lsb[0];
}

// 48x48 product: D = A (global row-major 48x64) x W (LDS col-major stride PST), in place.
// Returns pow2 scale exponent removed. No barriers inside (single-wave safe).
__device__ __forceinline__ int chain_product(const bf16_t* __restrict__ A, bf16_t* Ub, int lane) {
    const int half = lane >> 5;
    const int l31 = lane & 31;
    f32x16 z16;
#pragma unroll
    for (int r = 0; r < 16; r++) z16[r] = 0.0f;

    bf16x8 af[2][3];
#pragma unroll
    for (int mt = 0; mt < 2; mt++) {
        int m = l31 + 32 * mt;
#pragma unroll
        for (int ks = 0; ks < 3; ks++) {
            if (m < KK)
                af[mt][ks] = __builtin_bit_cast(bf16x8, *(const uint4*)&A[(size_t)m * 64 + 16 * ks + 8 * half]);
            else
                af[mt][ks] = __builtin_bit_cast(bf16x8, make_uint4(0, 0, 0, 0));
        }
    }
    bf16x8 bg[3][2];
#pragma unroll
    for (int ks = 0; ks < 3; ks++)
#pragma unroll
        for (int nt = 0; nt < 2; nt++)
            bg[ks][nt] = __builtin_bit_cast(bf16x8, *(const uint4*)&Ub[(l31 + 32 * nt) * PST + 16 * ks + 8 * half]);

    f32x16 acc[4];
#pragma unroll
    for (int mt = 0; mt < 2; mt++)
#pragma unroll
        for (int nt = 0; nt < 2; nt++) {
            f32x16 a0 = __builtin_amdgcn_mfma_f32_32x32x16_bf16(af[mt][0], bg[0][nt], z16, 0, 0, 0);
            a0 = __builtin_amdgcn_mfma_f32_32x32x16_bf16(af[mt][1], bg[1][nt], a0, 0, 0, 0);
            acc[mt * 2 + nt] = __builtin_amdgcn_mfma_f32_32x32x16_bf16(af[mt][2], bg[2][nt], a0, 0, 0, 0);
        }

    float v00 = rdlanef(acc[0][0], 0);
    int k = (int)(__float_as_uint(v00) >> 23) - 127;
    float r = __uint_as_float((unsigned int)(127 - k) << 23);

#pragma unroll
    for (int mt = 0; mt < 2; mt++)
#pragma unroll
        for (int nt = 0; nt < 2; nt++) {
            int c = l31 + 32 * nt;
#pragma unroll
            for (int g = 0; g < 4; g++) {
                int a0 = 32 * mt + 8 * g + 4 * half;
                if (a0 < KK) {
                    const f32x16& Aq = acc[mt * 2 + nt];
                    unsigned int u0 = bf16bits(Aq[4 * g + 0] * r) | (bf16bits(Aq[4 * g + 1] * r) << 16);
                    unsigned int u1 = bf16bits(Aq[4 * g + 2] * r) | (bf16bits(Aq[4 * g + 3] * r) << 16);
                    *(uint2*)&Ub[c * PST + a0] = make_uint2(u0, u1);
                }
            }
        }
    return k;
}

// Variant: A read from LDS col-major slot (A[m][k] = As[k*PST + m]).
__device__ __forceinline__ int chain_product_ldsA(const bf16_t* As, bf16_t* Ub, int lane) {
    const int half = lane >> 5;
    const int l31 = lane & 31;
    f32x16 z16;
#pragma unroll
    for (int r = 0; r < 16; r++) z16[r] = 0.0f;

    bf16x8 af[2][3];
#pragma unroll
    for (int mt = 0; mt < 2; mt++) {
        int m = l31 + 32 * mt;
#pragma unroll
        for (int ks = 0; ks < 3; ks++) {
            bf16x8 f;
#pragma unroll
            for (int j = 0; j < 8; j++) {
                int k = 16 * ks + 8 * half + j;
                f[j] = (m < KK) ? As[k * PST + m] : (bf16_t)0.0f;
            }
            af[mt][ks] = f;
        }
    }
    bf16x8 bg[3][2];
#pragma unroll
    for (int ks = 0; ks < 3; ks++)
#pragma unroll
        for (int nt = 0; nt < 2; nt++)
            bg[ks][nt] = __builtin_bit_cast(bf16x8, *(const uint4*)&Ub[(l31 + 32 * nt) * PST + 16 * ks + 8 * half]);

    f32x16 acc[4];
#pragma unroll
    for (int mt = 0; mt < 2; mt++)
#pragma unroll
        for (int nt = 0; nt < 2; nt++) {
            f32x16 a0 = __builtin_amdgcn_mfma_f32_32x32x16_bf16(af[mt][0], bg[0][nt], z16, 0, 0, 0);
            a0 = __builtin_amdgcn_mfma_f32_32x32x16_bf16(af[mt][1], bg[1][nt], a0, 0, 0, 0);
            acc[mt * 2 + nt] = __builtin_amdgcn_mfma_f32_32x32x16_bf16(af[mt][2], bg[2][nt], a0, 0, 0, 0);
        }

    float v00 = rdlanef(acc[0][0], 0);
    int k = (int)(__float_as_uint(v00) >> 23) - 127;
    float r = __uint_as_float((unsigned int)(127 - k) << 23);

#pragma unroll
    for (int mt = 0; mt < 2; mt++)
#pragma unroll
        for (int nt = 0; nt < 2; nt++) {
            int c = l31 + 32 * nt;
#pragma unroll
            for (int g = 0; g < 4; g++) {
                int a0 = 32 * mt + 8 * g + 4 * half;
                if (a0 < KK) {
                    const f32x16& Aq = acc[mt * 2 + nt];
                    unsigned int u0 = bf16bits(Aq[4 * g + 0] * r) | (bf16bits(Aq[4 * g + 1] * r) << 16);
                    unsigned int u1 = bf16bits(Aq[4 * g + 2] * r) | (bf16bits(Aq[4 * g + 3] * r) << 16);
                    *(uint2*)&Ub[c * PST + a0] = make_uint2(u0, u1);
                }
            }
        }
    return k;
}

// ============ phaseAB: one kernel — 4-wave fold of all segments + q0 + output ============
__global__ __launch_bounds__(256) void phaseAB_kernel(
    const float* __restrict__ y_pred, const bf16_t* __restrict__ ws_u,
    const int* __restrict__ ws_ls, const float* __restrict__ ws_target,
    float* __restrict__ out, int nseg) {
    const int b = blockIdx.x;
    const int tid = threadIdx.x;
    const int w = tid >> 6;
    const int lane = tid & 63;
    const int per = nseg / 4;       // segments per wave

    __shared__ __align__(16) bf16_t Ws[4][64 * PST];   // 4 x 7 KB
    __shared__ int lsw[4];

    // wave w: load its first segment, fold the remaining per-1 serially
    const int base = b * nseg + w * per;
    const bf16_t* s0 = ws_u + (size_t)base * 3072;
    for (int k = 0; k < KK; k++)
        Ws[w][lane * PST + k] = (lane < KK) ? s0[(size_t)k * 64 + lane] : (bf16_t)0.0f;
    int lsk = ws_ls[base];
    for (int j = 1; j < per; j++) {
        const bf16_t* A = ws_u + (size_t)(base + j) * 3072;
        lsk += ws_ls[base + j];
        lsk += chain_product(A, Ws[w], lane);
    }
    if (lane == 0) lsw[w] = lsk;
    __syncthreads();

    if (w == 0) {
        int ls2 = 0;
#pragma unroll
        for (int j = 1; j < 4; j++) ls2 += chain_product_ldsA(Ws[j], Ws[0], lane);

        float L = (float)(lsw[0] + lsw[1] + lsw[2] + lsw[3] + ls2);

        // q0 from t=0 row
        float x0 = (lane < KK) ? y_pred[(size_t)b * TT * KK + lane] : 0.0f;
        bool ok0 = (lane >= KK) || (x0 > -1e6f);
        bool m0 = (__ballot(ok0) == ~0ull);
        float xeff = (lane < KK) ? (m0 ? x0 : 0.0f) : 0.0f;
        float c0 = rdlanef(xeff, 0);
        float q0 = (lane < KK) ? fexp(xeff - c0) : 0.0f;

        float p = 0.0f;
        if (lane < KK) {
            for (int c = 0; c < KK; c++) {
                float qc = rdlanef(q0, c);
                p = fmaf(bf2f(Ws[0][c * PST + lane]), qc, p);
            }
        }
#pragma unroll
        for (int off = 32; off; off >>= 1) p += __shfl_xor(p, off);

        // target = sum of per-block partials
        float tg = (lane < nseg) ? ws_target[b * nseg + lane] : 0.0f;
#pragma unroll
        for (int off = 32; off; off >>= 1) tg += __shfl_xor(tg, off);

        if (lane == 0) {
            out[b] = c0 + 0.6931471805599453f * (L + flog2(p)) - tg;
        }
    }
}

extern "C" void kernel_launch(void* const* d_in, const int* in_sizes, int n_in,
                              void* d_out, int out_size, void* d_ws, size_t ws_size,
                              hipStream_t stream) {
    const float* y_true = (const float*)d_in[0];
    const float* y_pred = (const float*)d_in[1];
    const float* trans = (const float*)d_in[2];
    float* out = (float*)d_out;

    // adaptive segment count (r3 lesson: never overrun d_ws)
    int nseg = 16;
    if (ws_size >= (size_t)WS_U_OFF + (size_t)BB * 64 * SEGBYTES) nseg = 64;
    else if (ws_size >= (size_t)WS_U_OFF + (size_t)BB * 32 * SEGBYTES) nseg = 32;

    float* ws_target = (float*)d_ws;                          // BB*nseg floats (<=16 KB)
    int* ws_ls = (int*)((char*)d_ws + WS_LS_OFF);             // BB*nseg ints  (<=16 KB)
    bf16_t* ws_u = (bf16_t*)((char*)d_ws + WS_U_OFF);

    fused_kernel<<<dim3(nseg, BB), 256, 0, stream>>>(
        y_true, y_pred, trans, ws_target, ws_ls, ws_u, nseg);
    phaseAB_kernel<<<BB, 256, 0, stream>>>(y_pred, ws_u, ws_ls, ws_target, out, nseg);
}